// Round 5
// baseline (73.692 us; speedup 1.0000x reference)
//
#include <hip/hip_runtime.h>
#include <hip/hip_bf16.h>

// MemristorLinearLayer == x @ W^T + bias exactly (G_OFF/k_G/k_I all cancel).
// Latency-optimized bf16 MFMA GEMM, M=256 N=1024 K=1024.
// No LDS staging (inputs are 5 MB, L2-resident): each wave loads its MFMA
// fragments straight from global, converts fp32->bf16 in regs, no K-loop
// barriers. 256 blocks (1/CU) x 8 waves; 2-way in-block split-K halves the
// serial MFMA chain and gives 2 waves/SIMD for latency hiding; one LDS
// reduce + single barrier at the end.

typedef __attribute__((ext_vector_type(4))) float  f32x4;
typedef __attribute__((ext_vector_type(8))) short  bf16x8;

#define BATCH    256
#define SIZE_IN  1024
#define SIZE_OUT 1024

static __device__ inline bf16x8 pack8(f32x4 lo, f32x4 hi) {
    union { struct { __hip_bfloat162 a, b, c, d; } h; bf16x8 v; } u;
    float2 f;
    f.x = lo.x; f.y = lo.y; u.h.a = __float22bfloat162_rn(f);
    f.x = lo.z; f.y = lo.w; u.h.b = __float22bfloat162_rn(f);
    f.x = hi.x; f.y = hi.y; u.h.c = __float22bfloat162_rn(f);
    f.x = hi.z; f.y = hi.w; u.h.d = __float22bfloat162_rn(f);
    return u.v;
}

__global__ __launch_bounds__(512, 2)
void memristor_gemm(const float* __restrict__ X, const float* __restrict__ W,
                    const float* __restrict__ bias, float* __restrict__ out) {
    __shared__ f32x4 red[4][64];      // 4 KB: split-K partial sums

    const int t    = threadIdx.x;
    const int lane = t & 63;
    const int wid  = t >> 6;          // wave 0..7
    const int ks   = wid >> 2;        // K-half: 0 -> [0,512), 1 -> [512,1024)
    const int wq   = wid & 3;         // output quadrant 0..3
    const int wr   = wq >> 1;         // quadrant row 0..1
    const int wc   = wq & 1;          // quadrant col 0..1
    const int fr   = lane & 15;       // fragment row (A) / col (B) within 16
    const int fg   = lane >> 4;       // k-group 0..3 (8 elems each)

    const int brow = blockIdx.y * 32;
    const int bcol = blockIdx.x * 32;

    // fragment layout (refcheck'd round 3): lane holds row fr, k = fg*8..fg*8+7
    const float* Ap = X + (size_t)(brow + wr * 16 + fr) * SIZE_IN + ks * 512 + fg * 8;
    const float* Bp = W + (size_t)(bcol + wc * 16 + fr) * SIZE_IN + ks * 512 + fg * 8;

    f32x4 acc = {0.f, 0.f, 0.f, 0.f};
    #pragma unroll
    for (int kk = 0; kk < 16; ++kk) {
        f32x4 a0 = *(const f32x4*)(Ap + kk * 32);
        f32x4 a1 = *(const f32x4*)(Ap + kk * 32 + 4);
        f32x4 b0 = *(const f32x4*)(Bp + kk * 32);
        f32x4 b1 = *(const f32x4*)(Bp + kk * 32 + 4);
        acc = __builtin_amdgcn_mfma_f32_16x16x32_bf16(pack8(a0, a1), pack8(b0, b1),
                                                      acc, 0, 0, 0);
    }

    if (ks == 1) red[wq][lane] = acc;
    __syncthreads();
    if (ks == 0) {
        const f32x4 other = red[wq][lane];
        const int col    = bcol + wc * 16 + fr;
        const float bv   = bias[col];
        const int row0   = brow + wr * 16 + fg * 4;   // C/D layout: col=lane&15, row=(lane>>4)*4+j
        #pragma unroll
        for (int j = 0; j < 4; ++j)
            out[(size_t)(row0 + j) * SIZE_OUT + col] = acc[j] + other[j] + bv;
    }
}

extern "C" void kernel_launch(void* const* d_in, const int* in_sizes, int n_in,
                              void* d_out, int out_size, void* d_ws, size_t ws_size,
                              hipStream_t stream) {
    const float* x  = (const float*)d_in[0];   // [256,1024]
    const float* w  = (const float*)d_in[1];   // [1024,1024] row-major (out,in)
    const float* b  = (const float*)d_in[2];   // [1024]
    float* out      = (float*)d_out;           // [256,1024]

    dim3 grid(SIZE_OUT / 32, BATCH / 32);      // (32, 8) = 256 blocks, 1/CU
    dim3 block(512);                           // 8 waves
    hipLaunchKernelGGL(memristor_gemm, grid, block, 0, stream, x, w, b, out);
}